// Round 1
// baseline (18353.532 us; speedup 1.0000x reference)
//
#include <hip/hip_runtime.h>
#include <stdint.h>
#include <stddef.h>

#define SEQ 1024
#define BATCH 64
#define HID 512   // H == D == 512

typedef short short8 __attribute__((ext_vector_type(8)));
typedef float floatx4 __attribute__((ext_vector_type(4)));

// ---- bf16 helpers (manual, RTN-even) ----
__device__ __forceinline__ unsigned short f2bf(float f) {
    unsigned u = __builtin_bit_cast(unsigned, f);
    u = (u + 0x7FFFu + ((u >> 16) & 1u)) >> 16;
    return (unsigned short)u;
}
__device__ __forceinline__ float bf2f(unsigned short b) {
    unsigned u = ((unsigned)b) << 16;
    return __builtin_bit_cast(float, u);
}

// ---- prep: split x (fp32 -> bf16 hi + bf16 lo), vectorized ----
__global__ void split_x_kernel(const float* __restrict__ x,
                               unsigned short* __restrict__ xh,
                               unsigned short* __restrict__ xl, int n4) {
    int idx = blockIdx.x * blockDim.x + threadIdx.x;
    int stride = gridDim.x * blockDim.x;
    const float4* x4 = (const float4*)x;
    for (int i = idx; i < n4; i += stride) {
        float4 v = x4[i];
        ushort4 h, l;
        h.x = f2bf(v.x); l.x = f2bf(v.x - bf2f(h.x));
        h.y = f2bf(v.y); l.y = f2bf(v.y - bf2f(h.y));
        h.z = f2bf(v.z); l.z = f2bf(v.z - bf2f(h.z));
        h.w = f2bf(v.w); l.w = f2bf(v.w - bf2f(h.w));
        *(ushort4*)(xh + 4 * (size_t)i) = h;
        *(ushort4*)(xl + 4 * (size_t)i) = l;
    }
}

// ---- prep: transpose + split the 4 weight matrices; also bias sums ----
// Input W[k][n] (in,out) row-major fp32; output Wt[n][k] bf16 hi/lo so that the
// MFMA B-fragment (8 contiguous k for fixed n) is a single 16B load.
__global__ void prep_w_kernel(const float* __restrict__ Wx0, const float* __restrict__ bx0,
                              const float* __restrict__ Wh0, const float* __restrict__ bh0,
                              const float* __restrict__ Wx1, const float* __restrict__ bx1,
                              const float* __restrict__ Wh1, const float* __restrict__ bh1,
                              unsigned short* __restrict__ Wth,
                              unsigned short* __restrict__ Wtl,
                              float* __restrict__ bsum) {
    int b = blockIdx.x;               // 0..2047
    int mat = b >> 9, k = b & 511;
    const float* Wsrc = (mat == 0) ? Wx0 : (mat == 1) ? Wh0 : (mat == 2) ? Wx1 : Wh1;
    for (int n = threadIdx.x; n < HID; n += blockDim.x) {
        float w = Wsrc[k * HID + n];
        unsigned short hi = f2bf(w);
        unsigned short lo = f2bf(w - bf2f(hi));
        size_t o = (size_t)mat * HID * HID + (size_t)n * HID + k;
        Wth[o] = hi;
        Wtl[o] = lo;
    }
    if (b == 0) for (int c = threadIdx.x; c < HID; c += blockDim.x) bsum[c] = bx0[c] + bh0[c];
    if (b == 1) for (int c = threadIdx.x; c < HID; c += blockDim.x) bsum[HID + c] = bx1[c] + bh1[c];
}

// ---- prep: init parity-1 h buffers from h0 input (zeros in practice) ----
// h buffer layout: [layer(2)][parity(2)][64*512] for both hi and lo arrays.
__global__ void init_h_kernel(const float* __restrict__ h0in,
                              unsigned short* __restrict__ hh,
                              unsigned short* __restrict__ hl) {
    int i = blockIdx.x * blockDim.x + threadIdx.x;   // 0..65535
    if (i >= 2 * BATCH * HID) return;
    int l = i >> 15, r = i & 32767;
    float v = h0in[i];
    unsigned short hi = f2bf(v), lo = f2bf(v - bf2f(hi));
    size_t o = (size_t)(l * 2 + 1) * (BATCH * HID) + r;
    hh[o] = hi;
    hl[o] = lo;
}

// ---- one pipeline super-step: L0 computes h0[s], L1 computes h1[s-1] ----
// grid = 64 blocks x 256 threads. Block: [layer(2)][rowgroup(4)][colgroup(8)].
// Each wave owns a 16x16 output tile column-slice (wave -> 16 cols of the wg's 64).
// hi/lo bf16 split on both operands: logical A@W = Ah@Wh + Al@Wh + Ah@Wl.
__global__ __launch_bounds__(256) void rnn_step_kernel(
    int s,
    const unsigned short* __restrict__ xh, const unsigned short* __restrict__ xl,
    const unsigned short* __restrict__ Wth, const unsigned short* __restrict__ Wtl,
    const float* __restrict__ bsum,
    unsigned short* __restrict__ hh, unsigned short* __restrict__ hl,
    float* __restrict__ out) {
    const int HB = BATCH * HID;  // one h buffer slab
    int wg = blockIdx.x;
    int layer = wg >> 5;
    int rg = (wg >> 3) & 3;
    int cg = wg & 7;
    int wave = threadIdx.x >> 6;
    int lane = threadIdx.x & 63;
    int lr = lane & 15, quad = lane >> 4;
    int col = cg * 64 + wave * 16 + lr;   // output column (0..511)
    int row0 = rg * 16;

    const unsigned short *A1h, *A1l, *A2h, *A2l, *W1h, *W1l, *W2h, *W2l;
    int t;
    if (layer == 0) {
        if (s >= SEQ) return;
        t = s;
        A1h = xh + (size_t)(t * BATCH + row0) * HID;            // x[t]
        A1l = xl + (size_t)(t * BATCH + row0) * HID;
        int parR = (s + 1) & 1;                                 // h0[s-1]
        A2h = hh + (size_t)(0 * 2 + parR) * HB + row0 * HID;
        A2l = hl + (size_t)(0 * 2 + parR) * HB + row0 * HID;
        W1h = Wth + 0 * (size_t)HID * HID; W1l = Wtl + 0 * (size_t)HID * HID;  // Wx0
        W2h = Wth + 1 * (size_t)HID * HID; W2l = Wtl + 1 * (size_t)HID * HID;  // Wh0
    } else {
        if (s < 1) return;
        t = s - 1;
        int parA = t & 1;                                       // h0[t] (written at super-step t)
        A1h = hh + (size_t)(0 * 2 + parA) * HB + row0 * HID;
        A1l = hl + (size_t)(0 * 2 + parA) * HB + row0 * HID;
        int parB = (t + 1) & 1;                                 // h1[t-1]
        A2h = hh + (size_t)(1 * 2 + parB) * HB + row0 * HID;
        A2l = hl + (size_t)(1 * 2 + parB) * HB + row0 * HID;
        W1h = Wth + 2 * (size_t)HID * HID; W1l = Wtl + 2 * (size_t)HID * HID;  // Wx1
        W2h = Wth + 3 * (size_t)HID * HID; W2l = Wtl + 3 * (size_t)HID * HID;  // Wh1
    }
    float bv = bsum[layer * HID + col];

    // per-lane fragment offsets: A[m=lane&15][k=quad*8+j], B[n=lane&15][k=quad*8+j]
    size_t aoff = (size_t)lr * HID + quad * 8;
    size_t woff = (size_t)col * HID + quad * 8;

    floatx4 accA = {0.f, 0.f, 0.f, 0.f};
    floatx4 accB = {0.f, 0.f, 0.f, 0.f};
#pragma unroll
    for (int kt = 0; kt < 16; ++kt) {
        int ko = kt * 32;
        short8 a1h = *(const short8*)(A1h + aoff + ko);
        short8 a1l = *(const short8*)(A1l + aoff + ko);
        short8 a2h = *(const short8*)(A2h + aoff + ko);
        short8 a2l = *(const short8*)(A2l + aoff + ko);
        short8 w1h = *(const short8*)(W1h + woff + ko);
        short8 w1l = *(const short8*)(W1l + woff + ko);
        short8 w2h = *(const short8*)(W2h + woff + ko);
        short8 w2l = *(const short8*)(W2l + woff + ko);
        // balanced chains: 3 per accumulator per kt
        accA = __builtin_amdgcn_mfma_f32_16x16x32_bf16(a1h, w1h, accA, 0, 0, 0);
        accB = __builtin_amdgcn_mfma_f32_16x16x32_bf16(a1l, w1h, accB, 0, 0, 0);
        accA = __builtin_amdgcn_mfma_f32_16x16x32_bf16(a1h, w1l, accA, 0, 0, 0);
        accB = __builtin_amdgcn_mfma_f32_16x16x32_bf16(a2h, w2h, accB, 0, 0, 0);
        accA = __builtin_amdgcn_mfma_f32_16x16x32_bf16(a2l, w2h, accA, 0, 0, 0);
        accB = __builtin_amdgcn_mfma_f32_16x16x32_bf16(a2h, w2l, accB, 0, 0, 0);
    }

    // epilogue: C/D layout col=lane&15, row=quad*4+reg
    int parOut = t & 1;
    unsigned short* hhout = hh + (size_t)(layer * 2 + parOut) * HB;
    unsigned short* hlout = hl + (size_t)(layer * 2 + parOut) * HB;
#pragma unroll
    for (int i = 0; i < 4; ++i) {
        int row = row0 + quad * 4 + i;
        float p = accA[i] + accB[i] + bv;
        // tanh(p) = 1 - 2/(exp(2p)+1): monotone, saturates correctly at +/-inf
        float e = __expf(2.0f * p);
        float th = 1.0f - 2.0f / (e + 1.0f);
        unsigned short thi = f2bf(th);
        unsigned short tlo = f2bf(th - bf2f(thi));
        hhout[(size_t)row * HID + col] = thi;
        hlout[(size_t)row * HID + col] = tlo;
        if (layer == 1) {
            out[((size_t)t * BATCH + row) * HID + col] = th;          // outputs[t]
            if (t == SEQ - 1)
                out[(size_t)SEQ * BATCH * HID + (size_t)(1 * BATCH + row) * HID + col] = th;
        } else if (t == SEQ - 1) {
            out[(size_t)SEQ * BATCH * HID + (size_t)(0 * BATCH + row) * HID + col] = th;
        }
    }
}

extern "C" void kernel_launch(void* const* d_in, const int* in_sizes, int n_in,
                              void* d_out, int out_size, void* d_ws, size_t ws_size,
                              hipStream_t stream) {
    const float* x    = (const float*)d_in[0];
    const float* h0in = (const float*)d_in[1];
    const float* Wx0  = (const float*)d_in[2];
    const float* bx0  = (const float*)d_in[3];
    const float* Wh0  = (const float*)d_in[4];
    const float* bh0  = (const float*)d_in[5];
    const float* Wx1  = (const float*)d_in[6];
    const float* bx1  = (const float*)d_in[7];
    const float* Wh1  = (const float*)d_in[8];
    const float* bh1  = (const float*)d_in[9];
    float* out = (float*)d_out;

    // workspace layout (all 256B aligned)
    char* w = (char*)d_ws;
    const size_t XN = (size_t)SEQ * BATCH * HID;          // 33,554,432
    unsigned short* xh  = (unsigned short*)(w);                       // 64 MB
    unsigned short* xl  = (unsigned short*)(w + 2 * XN);              // 64 MB
    unsigned short* Wth = (unsigned short*)(w + 4 * XN);              // 2 MB
    unsigned short* Wtl = (unsigned short*)(w + 4 * XN + 2097152);    // 2 MB
    float*          bsum= (float*)        (w + 4 * XN + 4194304);     // 4 KB
    unsigned short* hh  = (unsigned short*)(w + 4 * XN + 4198400);    // 256 KB
    unsigned short* hl  = (unsigned short*)(w + 4 * XN + 4460544);    // 256 KB
    // total ~132.5 MB

    split_x_kernel<<<4096, 256, 0, stream>>>(x, xh, xl, (int)(XN / 4));
    prep_w_kernel<<<2048, 256, 0, stream>>>(Wx0, bx0, Wh0, bh0, Wx1, bx1, Wh1, bh1,
                                            Wth, Wtl, bsum);
    init_h_kernel<<<256, 256, 0, stream>>>(h0in, hh, hl);

    // pipelined scan: super-step s does L0(t=s) and L1(t=s-1); kernel boundary = barrier
    for (int s = 0; s <= SEQ; ++s) {
        rnn_step_kernel<<<64, 256, 0, stream>>>(s, xh, xl, Wth, Wtl, bsum, hh, hl, out);
    }
}